// Round 12
// baseline (28.410 us; speedup 1.0000x reference)
//
#include <hip/hip_runtime.h>
#include <hip/hip_bf16.h>

#define BB 4
#define TT 2048
#define DD 128
#define CHK 64
#define NCHK 32            // TT/CHK
#define NCHKS (BB*NCHK)    // 128 chunks total

typedef __attribute__((ext_vector_type(8))) short  bf16x8;
typedef __attribute__((ext_vector_type(4))) float  f32x4;

#define MFMA(a,b,c) __builtin_amdgcn_mfma_f32_16x16x32_bf16(a, b, c, 0, 0, 0)

__device__ __forceinline__ short f2b(float f) {
    union { float f; unsigned u; } x; x.f = f;
    unsigned r = x.u + 0x7fffu + ((x.u >> 16) & 1u);   // RNE
    return (short)(r >> 16);
}
__device__ __forceinline__ float b2f(short s) {
    union { unsigned u; float f; } x; x.u = ((unsigned)(unsigned short)s) << 16;
    return x.f;
}
__device__ __forceinline__ bf16x8 cvt8(const float* p) {
    float4 a = *(const float4*)p, b = *(const float4*)(p + 4);
    bf16x8 r;
    r[0]=f2b(a.x); r[1]=f2b(a.y); r[2]=f2b(a.z); r[3]=f2b(a.w);
    r[4]=f2b(b.x); r[5]=f2b(b.y); r[6]=f2b(b.z); r[7]=f2b(b.w);
    return r;
}

// ---------------------------------------------------------------------------
// K1: ONE block per chunk, 1024 threads (16 waves). All inputs read ONCE:
//     q,k -> LDS bf16 (coalesced) -> A-frags from LDS; v -> vT; W -> Wl.
//     Wave (tq = w&3, eh = w>>2): phi(q),phi(k) for t-strip 16tq, e-quarter
//     32eh. Outputs overwrite qs/ks row-major (Qf/Kf) + KfT transposed.
//     Copy-out Qf/Kf/z/vT; S-GEMM (wave w: d-tile w>>1, e-tiles 4(w&1)..+3)
//     -> st[e][d] ([128][136]!) -> Ss_g bf16.
// grid 128 x 1024. LDS ~138 KB -> 1 block/CU, 16 waves (4/SIMD).
// ---------------------------------------------------------------------------
__global__ __launch_bounds__(1024) void k1_chunk(const float* __restrict__ q,
                                                 const float* __restrict__ kin,
                                                 const float* __restrict__ vin,
                                                 const float* __restrict__ W,
                                                 const float* __restrict__ bias,
                                                 short* __restrict__ Ss_g,
                                                 float* __restrict__ zc_g,
                                                 short* __restrict__ vT_g,
                                                 short* __restrict__ Qf_g,
                                                 short* __restrict__ Kf_g) {
    int c = blockIdx.x;
    const float* qc = q   + (size_t)c * CHK * DD;
    const float* kc = kin + (size_t)c * CHK * DD;
    const float* vc = vin + (size_t)c * CHK * DD;

    __shared__ __align__(16) short Wl [DD][DD + 8];     // 34816 B
    __shared__ __align__(16) short qs [CHK][DD + 8];    // 17408 B  in: q bf16; out: Qf
    __shared__ __align__(16) short ks [CHK][DD + 8];    // 17408 B  in: k bf16; out: Kf
    __shared__ __align__(16) short KfT[DD][CHK + 8];    // 18432 B  (KfT[d][t])
    __shared__ __align__(16) short vT [DD][CHK + 8];    // 18432 B  (vT[e][t])
    __shared__ __align__(16) short st [DD][DD + 8];     // 34816 B  Ss[e][d], d = 0..127

    int tid = threadIdx.x, lane = tid & 63, w = tid >> 6;
    int l15 = lane & 15, l4 = lane >> 4;
    int tq = w & 3, eh = w >> 2;
    const f32x4 z4 = {0.f, 0.f, 0.f, 0.f};

    // ---- stage W (4096 float4s), q,k (1024 x 8 floats each), vT ----
    #pragma unroll
    for (int it = 0; it < 4; ++it) {
        int i = tid + it * 1024;
        int row = i >> 5, c4 = (i & 31) * 4;
        float4 v = *(const float4*)(W + (size_t)row * DD + c4);
        unsigned lo = (unsigned short)f2b(v.x) | ((unsigned)(unsigned short)f2b(v.y) << 16);
        unsigned hi = (unsigned short)f2b(v.z) | ((unsigned)(unsigned short)f2b(v.w) << 16);
        uint2 p; p.x = lo; p.y = hi;
        *(uint2*)&Wl[row][c4] = p;
    }
    {
        int row = tid >> 4, col8 = (tid & 15) * 8;      // 1024 = 64 x 16
        *(bf16x8*)&qs[row][col8] = cvt8(qc + row * DD + col8);
        *(bf16x8*)&ks[row][col8] = cvt8(kc + row * DD + col8);
    }
    #pragma unroll
    for (int it = 0; it < 2; ++it) {
        int i = tid + it * 1024;                        // 2048 float4s
        int t = i >> 5, e4 = (i & 31) * 4;
        float4 vv = *(const float4*)(vc + t * DD + e4);
        vT[e4 + 0][t] = f2b(vv.x); vT[e4 + 1][t] = f2b(vv.y);
        vT[e4 + 2][t] = f2b(vv.z); vT[e4 + 3][t] = f2b(vv.w);
    }
    __syncthreads();

    // ---- load A-fragments for this wave's t-strip (registers) ----
    bf16x8 afq[4], afk[4];
    {
        int row = 16 * tq + l15;
        #pragma unroll
        for (int kk = 0; kk < 4; ++kk) {
            afq[kk] = *(const bf16x8*)&qs[row][kk * 32 + l4 * 8];
            afk[kk] = *(const bf16x8*)&ks[row][kk * 32 + l4 * 8];
        }
    }
    __syncthreads();   // all frag reads done before outputs overwrite qs/ks

    // ---- phi(q), phi(k): e = 32 eh + 16 n + l15, n = 0..1 ----
    #pragma unroll
    for (int n = 0; n < 2; ++n) {
        int e = 32 * eh + 16 * n + l15;
        f32x4 dq = z4, dk = z4;
        #pragma unroll
        for (int kk = 0; kk < 4; ++kk) {
            bf16x8 bw = *(const bf16x8*)&Wl[e][kk * 32 + l4 * 8];
            dq = MFMA(afq[kk], bw, dq);
            dk = MFMA(afk[kk], bw, dk);
        }
        float bv = bias[e];
        #pragma unroll
        for (int j = 0; j < 4; ++j) {
            int t = 16 * tq + l4 * 4 + j;
            float zq = dq[j] + bv;
            qs[t][e] = f2b((zq > 0.f) ? (zq + 1.f) : __expf(zq));   // Qf
            float zk = dk[j] + bv;
            short rk = f2b((zk > 0.f) ? (zk + 1.f) : __expf(zk));   // Kf
            ks[t][e] = rk;
            KfT[e][t] = rk;
        }
    }
    __syncthreads();

    // ---- copy-out Qf, Kf (1024 bf16x8 each); z_c; vT -> global ----
    {
        int t = tid >> 4, u = (tid & 15) * 8;
        *(bf16x8*)(Qf_g + (size_t)c * CHK * DD + t * DD + u) = *(const bf16x8*)&qs[t][u];
        *(bf16x8*)(Kf_g + (size_t)c * CHK * DD + t * DD + u) = *(const bf16x8*)&ks[t][u];
    }
    if (tid < DD) {
        float s = 0.f;
        #pragma unroll
        for (int t8 = 0; t8 < CHK / 8; ++t8) {
            bf16x8 kv = *(const bf16x8*)&KfT[tid][t8 * 8];
            #pragma unroll
            for (int j = 0; j < 8; ++j) s += b2f(kv[j]);
        }
        zc_g[(size_t)c * DD + tid] = s;
    }
    {
        int e = tid >> 3, t0 = (tid & 7) * 8;           // 1024 = 128 x 8
        *(bf16x8*)(vT_g + (size_t)c * DD * CHK + e * CHK + t0) = *(const bf16x8*)&vT[e][t0];
    }

    // ---- S-GEMM: S[d][e] = sum_t KfT[d][t] vT[e][t] ----
    // wave w: d-tile dt = w>>1 (16 rows), e-tiles n = 4(w&1)..+3
    {
        int dt = w >> 1, nb = 4 * (w & 1);
        f32x4 sacc[4];
        #pragma unroll
        for (int n = 0; n < 4; ++n) sacc[n] = z4;
        #pragma unroll
        for (int kk = 0; kk < 2; ++kk) {
            bf16x8 afr = *(const bf16x8*)&KfT[16 * dt + l15][kk * 32 + l4 * 8];
            #pragma unroll
            for (int n = 0; n < 4; ++n) {
                bf16x8 bfr = *(const bf16x8*)&vT[16 * (nb + n) + l15][kk * 32 + l4 * 8];
                sacc[n] = MFMA(afr, bfr, sacc[n]);
            }
        }
        // D: row = d (16dt + l4*4+j), col = e (16(nb+n)+l15) -> st[e][d]
        #pragma unroll
        for (int n = 0; n < 4; ++n) {
            int e = 16 * (nb + n) + l15;
            #pragma unroll
            for (int j = 0; j < 4; ++j)
                st[e][16 * dt + l4 * 4 + j] = f2b(sacc[n][j]);
        }
    }
    __syncthreads();

    // ---- st -> Ss_g bf16 [c][e][d]: 2048 bf16x8 ----
    short* dst = Ss_g + (size_t)c * DD * DD;
    #pragma unroll
    for (int it = 0; it < 2; ++it) {
        int i = tid + it * 1024;
        int e = i >> 4, u = (i & 15) * 8;
        *(bf16x8*)(dst + e * DD + u) = *(const bf16x8*)&st[e][u];
    }
}

// ---------------------------------------------------------------------------
// K2: exclusive prefix over chunks (bf16 in/out, fp32 accum).
// grid 512 = (b,e) x 128 thr (thread = d).
// ---------------------------------------------------------------------------
__global__ __launch_bounds__(128) void k2_scan(const short* __restrict__ Ss_g,
                                               const float* __restrict__ zc_g,
                                               short* __restrict__ Sp_g,
                                               float* __restrict__ zp_g) {
    int e = blockIdx.x & 127, b = blockIdx.x >> 7;
    int d = threadIdx.x;
    size_t base = ((size_t)(b * NCHK) * DD + e) * DD + d;
    const size_t stride = (size_t)DD * DD;

    float vals[NCHK];
    #pragma unroll
    for (int c2 = 0; c2 < NCHK; ++c2) vals[c2] = b2f(Ss_g[base + c2 * stride]);
    float run = 0.f;
    #pragma unroll
    for (int c2 = 0; c2 < NCHK; ++c2) {
        Sp_g[base + c2 * stride] = f2b(run);
        run += vals[c2];
    }
    if (e == 0) {
        float vz[NCHK];
        #pragma unroll
        for (int c2 = 0; c2 < NCHK; ++c2) vz[c2] = zc_g[(size_t)(b * NCHK + c2) * DD + d];
        float rz = 0.f;
        #pragma unroll
        for (int c2 = 0; c2 < NCHK; ++c2) {
            zp_g[(size_t)(b * NCHK + c2) * DD + d] = rz;
            rz += vz[c2];
        }
    }
}

// ---------------------------------------------------------------------------
// K3: block (c, h): epilogue (R10). Qf, Kf -> LDS; QK^T causal with in-reg
//     masked rowsum; den via virtual zp-column MFMA + shfl_xor;
//     out half = Ps@V + Q@Sp; divide; store.
// grid 256 x 256. LDS ~44.3 KB.
// ---------------------------------------------------------------------------
__global__ __launch_bounds__(256) void k3_out(const short* __restrict__ Qf_g,
                                              const short* __restrict__ Kf_g,
                                              const short* __restrict__ Sp_g,
                                              const float* __restrict__ zp_g,
                                              const short* __restrict__ vT_g,
                                              float* __restrict__ out) {
    int c = blockIdx.x >> 1, h = blockIdx.x & 1;

    __shared__ __align__(16) short Qf[CHK][DD + 8];    // 17408 B
    __shared__ __align__(16) short Kf[CHK][DD + 8];    // 17408 B
    __shared__ __align__(16) short Ps[CHK][CHK + 8];   // 9216 B
    __shared__ float den[CHK];

    int tid = threadIdx.x, lane = tid & 63, w = tid >> 6;
    int l15 = lane & 15, l4 = lane >> 4;
    const f32x4 z4 = {0.f, 0.f, 0.f, 0.f};

    // virtual zp column B-frags (fragment row l15==0 carries zp, else 0)
    const float* zp = zp_g + (size_t)c * DD;
    bf16x8 bz[4];
    #pragma unroll
    for (int kk = 0; kk < 4; ++kk) {
        bf16x8 zf = cvt8(zp + kk * 32 + l4 * 8);
        bf16x8 zero = {0,0,0,0,0,0,0,0};
        bz[kk] = (l15 == 0) ? zf : zero;
    }

    // Qf, Kf global -> LDS (coalesced)
    {
        const short* srcq = Qf_g + (size_t)c * CHK * DD;
        const short* srck = Kf_g + (size_t)c * CHK * DD;
        #pragma unroll
        for (int it = 0; it < 4; ++it) {
            int i = tid + it * 256;           // 1024 bf16x8
            int t = i >> 4, u = (i & 15) * 8;
            *(bf16x8*)&Qf[t][u] = *(const bf16x8*)(srcq + t * DD + u);
            *(bf16x8*)&Kf[t][u] = *(const bf16x8*)(srck + t * DD + u);
        }
    }
    __syncthreads();

    // Q A-frags (rows t = 16w + l15)
    bf16x8 aq[4];
    #pragma unroll
    for (int kk = 0; kk < 4; ++kk)
        aq[kk] = *(const bf16x8*)&Qf[16 * w + l15][kk * 32 + l4 * 8];

    // q.zp via extra MFMA column
    f32x4 p4 = z4;
    #pragma unroll
    for (int kk = 0; kk < 4; ++kk) p4 = MFMA(aq[kk], bz[kk], p4);

    // QK^T causal -> Ps (wave-local rows); in-reg masked rowsum
    float rs[4] = {0.f, 0.f, 0.f, 0.f};
    #pragma unroll
    for (int n2 = 0; n2 < 4; ++n2) {
        f32x4 p = z4;
        #pragma unroll
        for (int kk = 0; kk < 4; ++kk) {
            bf16x8 bk = *(const bf16x8*)&Kf[16 * n2 + l15][kk * 32 + l4 * 8];
            p = MFMA(aq[kk], bk, p);
        }
        int t2 = 16 * n2 + l15;
        #pragma unroll
        for (int j = 0; j < 4; ++j) {
            int t = 16 * w + l4 * 4 + j;
            float pm = (t2 <= t) ? p[j] : 0.f;
            Ps[t][t2] = f2b(pm);
            rs[j] += pm;
        }
    }
    // reduce rowsum across l15 (lane bits 0..3)
    #pragma unroll
    for (int off = 1; off < 16; off <<= 1) {
        #pragma unroll
        for (int j = 0; j < 4; ++j) rs[j] += __shfl_xor(rs[j], off);
    }
    if (l15 == 0) {
        #pragma unroll
        for (int j = 0; j < 4; ++j)
            den[16 * w + l4 * 4 + j] = rs[j] + p4[j] + 1e-6f;
    }
    // Ps rows + den entries for this wave are wave-local; no barrier needed

    // out half: e = 64h + 16n + l15, n = 0..3
    bf16x8 ap[2];
    #pragma unroll
    for (int kk = 0; kk < 2; ++kk)
        ap[kk] = *(const bf16x8*)&Ps[16 * w + l15][kk * 32 + l4 * 8];

    const short* Sp  = Sp_g + (size_t)c * DD * DD;
    const short* vTg = vT_g + (size_t)c * DD * CHK;
    f32x4 oacc[4];
    #pragma unroll
    for (int n = 0; n < 4; ++n) oacc[n] = z4;
    #pragma unroll
    for (int n = 0; n < 4; ++n) {
        int e = 64 * h + 16 * n + l15;
        #pragma unroll
        for (int kk = 0; kk < 4; ++kk) {
            bf16x8 bs = *(const bf16x8*)(Sp + e * DD + kk * 32 + l4 * 8);
            oacc[n] = MFMA(aq[kk], bs, oacc[n]);
        }
        #pragma unroll
        for (int kk = 0; kk < 2; ++kk) {
            bf16x8 bv = *(const bf16x8*)(vTg + e * CHK + kk * 32 + l4 * 8);
            oacc[n] = MFMA(ap[kk], bv, oacc[n]);
        }
    }

    float* oc = out + (size_t)c * CHK * DD;
    float invs[4];
    #pragma unroll
    for (int j = 0; j < 4; ++j) invs[j] = 1.0f / den[16 * w + l4 * 4 + j];
    #pragma unroll
    for (int n = 0; n < 4; ++n) {
        int e = 64 * h + 16 * n + l15;
        #pragma unroll
        for (int j = 0; j < 4; ++j) {
            int t = 16 * w + l4 * 4 + j;
            oc[t * DD + e] = oacc[n][j] * invs[j];
        }
    }
}

// ---------------------------------------------------------------------------
extern "C" void kernel_launch(void* const* d_in, const int* in_sizes, int n_in,
                              void* d_out, int out_size, void* d_ws, size_t ws_size,
                              hipStream_t stream) {
    const float* q  = (const float*)d_in[0];
    const float* k  = (const float*)d_in[1];
    const float* v  = (const float*)d_in[2];
    const float* W  = (const float*)d_in[3];
    const float* bi = (const float*)d_in[4];
    float* out = (float*)d_out;

    float* zc_g = (float*)d_ws;                         // 16384 f32
    float* zp_g = zc_g + (size_t)NCHKS * DD;            // 16384 f32
    short* Ss_g = (short*)(zp_g + (size_t)NCHKS * DD);  // 4 MB
    short* Sp_g = Ss_g + (size_t)NCHKS * DD * DD;       // 4 MB
    short* vT_g = Sp_g + (size_t)NCHKS * DD * DD;       // 2 MB
    short* Qf_g = vT_g + (size_t)NCHKS * DD * CHK;      // 2 MB
    short* Kf_g = Qf_g + (size_t)NCHKS * CHK * DD;      // 2 MB

    k1_chunk<<<NCHKS, 1024, 0, stream>>>(q, k, v, W, bi, Ss_g, zc_g, vT_g, Qf_g, Kf_g);
    k2_scan<<<512, 128, 0, stream>>>(Ss_g, zc_g, Sp_g, zp_g);
    k3_out<<<2 * NCHKS, 256, 0, stream>>>(Qf_g, Kf_g, Sp_g, zp_g, vT_g, out);
}